// Round 7
// baseline (469.001 us; speedup 1.0000x reference)
//
#include <hip/hip_runtime.h>

typedef __attribute__((ext_vector_type(8))) short bf16x8;
typedef __attribute__((ext_vector_type(4))) float f32x4;

#define NBLK 512
#define NTHR 512
#define NWAVES (NBLK * 8)

__device__ __forceinline__ unsigned f2bf(float x) {
    unsigned u = __float_as_uint(x);
    return (u + 0x7fffu + ((u >> 16) & 1u)) >> 16;   // RNE f32->bf16
}

// device-scope grid barrier; all NBLK blocks guaranteed co-resident.
__device__ __forceinline__ void gbar(unsigned* bar) {
    __syncthreads();
    if (threadIdx.x == 0) {
        __threadfence();                               // release prior writes (agent)
        atomicAdd(bar, 1u);
        while (__hip_atomic_load(bar, __ATOMIC_ACQUIRE, __HIP_MEMORY_SCOPE_AGENT) < NBLK)
            __builtin_amdgcn_s_sleep(1);
        __threadfence();                               // acquire remote writes
    }
    __syncthreads();
}

__global__ __launch_bounds__(NTHR, 4) void k_all(
        const float* __restrict__ src, const float* __restrict__ tgt,
        const int* __restrict__ slab, const float* __restrict__ tlab,
        int ns, int N, int D, int C,
        int* __restrict__ clsrows, int* __restrict__ cnt_src, int* __restrict__ fill,
        unsigned* __restrict__ bars, double* __restrict__ gramsum,
        double* __restrict__ contrib,
        unsigned short* __restrict__ Xg, float* __restrict__ sqg, float* __restrict__ sgg,
        float* __restrict__ Pbuf, int capTiles, float* __restrict__ out) {
    const int tid = threadIdx.x;
    const int lane = tid & 63;
    const int w = tid >> 6;            // wave 0..7
    const int b = blockIdx.x;

    __shared__ int roS[33], tpoS[33], tS[32], presS[32];
    __shared__ float invbwS[32 * 5];
    __shared__ double inv_n2S[32];
    __shared__ int nTilesS;

    // ---- Phase A: labels (argmax for target), class counts, row lists ----
    for (int i = b * 8 + w; i < N; i += NWAVES) {
        int lab;
        if (i < ns) {
            lab = slab[i];
        } else {
            float v = -3.4e38f; int idx = C;
            if (lane < C) { v = tlab[(size_t)(i - ns) * C + lane]; idx = lane; }
            for (int o = 32; o; o >>= 1) {
                float v2 = __shfl_xor(v, o);
                int i2 = __shfl_xor(idx, o);
                if (v2 > v || (v2 == v && i2 < idx)) { v = v2; idx = i2; }  // first-max
            }
            lab = idx;
        }
        if (lane == 0) {
            if (i < ns) atomicAdd(&cnt_src[lab], 1);
            int pos = atomicAdd(&fill[lab], 1);
            clsrows[(size_t)lab * N + pos] = i;
        }
    }
    gbar(bars + 0);

    // ---- Phase B: per-block offsets into LDS (wave 0) ----
    if (w == 0) {
        int n = (lane < C) ? fill[lane] : 0;
        int nsrc = (lane < C) ? cnt_src[lane] : 0;
        int pres = (nsrc > 0 && (n - nsrc) > 0) ? 1 : 0;
        int T = pres ? (n + 31) / 32 : 0;
        int t2 = T * T;
        int sn = n, sp = t2;
        for (int o = 1; o < 64; o <<= 1) {
            int a = __shfl_up(sn, o), c2 = __shfl_up(sp, o);
            if (lane >= o) { sn += a; sp += c2; }
        }
        if (lane < C) {
            roS[lane] = sn - n; tpoS[lane] = sp - t2;
            tS[lane] = T; presS[lane] = pres;
            double nn = (double)n * (double)n; if (nn < 1.0) nn = 1.0;
            inv_n2S[lane] = 1.0 / nn;
        }
        if (lane == C - 1) { roS[C] = sn; tpoS[C] = sp; nTilesS = sp; }
    }
    __syncthreads();

    // ---- Phase C: gather rows class-contiguously as bf16; sq + sign ----
    for (int s = b * 8 + w; s < N; s += NWAVES) {
        int c = __popcll(__ballot((lane < C) && (roS[lane] <= s))) - 1;
        int g = clsrows[(size_t)c * N + (s - roS[c])];
        const float* row = (g < ns) ? src + (size_t)g * D : tgt + (size_t)(g - ns) * D;
        unsigned short* orow = Xg + (size_t)s * D;
        float acc = 0.f;
        for (int it = 0; it < D / 256; ++it) {
            float4 v = *(const float4*)(row + it * 256 + lane * 4);
            acc += v.x * v.x + v.y * v.y + v.z * v.z + v.w * v.w;
            uint2 p;
            p.x = f2bf(v.x) | (f2bf(v.y) << 16);
            p.y = f2bf(v.z) | (f2bf(v.w) << 16);
            *(uint2*)(orow + it * 256 + lane * 4) = p;
        }
        for (int o = 32; o; o >>= 1) acc += __shfl_down(acc, o);
        if (lane == 0) { sqg[s] = acc; sgg[s] = (g < ns) ? 1.f : -1.f; }
    }
    gbar(bars + 1);

    // ---- Phase D: split-K pair dots (MFMA) + per-class gram-sum ----
    {
        int nTiles = nTilesS;
        int nJobsK = nTiles * 4;
        int KC = D / 4;
        int kgrp = lane >> 4, lr = lane & 15, crow = (lane >> 4) * 4;
        for (int j = b * 8 + w; j < nJobsK; j += NWAVES) {
            int kc = j / nTiles;
            int tile = j - kc * nTiles;
            int c = __popcll(__ballot((lane < C) && (tpoS[lane] <= tile))) - 1;
            int t = tile - tpoS[c];
            int T = tS[c];
            int ti = t / T, tj = t - ti * T;
            int base = roS[c];
            int n = roS[c + 1] - base;

            int riA0 = min(ti * 32 + lr, n - 1), riA1 = min(ti * 32 + lr + 16, n - 1);
            int riB0 = min(tj * 32 + lr, n - 1), riB1 = min(tj * 32 + lr + 16, n - 1);
            const unsigned short* pA0 = Xg + (size_t)(base + riA0) * D + kc * KC + kgrp * 8;
            const unsigned short* pA1 = Xg + (size_t)(base + riA1) * D + kc * KC + kgrp * 8;
            const unsigned short* pB0 = Xg + (size_t)(base + riB0) * D + kc * KC + kgrp * 8;
            const unsigned short* pB1 = Xg + (size_t)(base + riB1) * D + kc * KC + kgrp * 8;

            f32x4 a00 = (f32x4){0.f, 0.f, 0.f, 0.f}, a01 = a00, a10 = a00, a11 = a00;
            #pragma unroll 4
            for (int k0 = 0; k0 < KC; k0 += 32) {
                bf16x8 va0 = *(const bf16x8*)(pA0 + k0);
                bf16x8 va1 = *(const bf16x8*)(pA1 + k0);
                bf16x8 vb0 = *(const bf16x8*)(pB0 + k0);
                bf16x8 vb1 = *(const bf16x8*)(pB1 + k0);
                a00 = __builtin_amdgcn_mfma_f32_16x16x32_bf16(va0, vb0, a00, 0, 0, 0);
                a01 = __builtin_amdgcn_mfma_f32_16x16x32_bf16(va0, vb1, a01, 0, 0, 0);
                a10 = __builtin_amdgcn_mfma_f32_16x16x32_bf16(va1, vb0, a10, 0, 0, 0);
                a11 = __builtin_amdgcn_mfma_f32_16x16x32_bf16(va1, vb1, a11, 0, 0, 0);
            }

            float gsum = 0.f;
            float* Pb = Pbuf + ((size_t)tile * 4 + kc) * 1024 + lane * 4;
            bool store = (tile < capTiles);
            // frag (fi,fj): rows ti*32+fi*16+crow+r, cols tj*32+fj*16+lr  [m89 layout]
            if (store) *(f32x4*)(Pb + 0 * 256) = a00;
            if (store) *(f32x4*)(Pb + 1 * 256) = a01;
            if (store) *(f32x4*)(Pb + 2 * 256) = a10;
            if (store) *(f32x4*)(Pb + 3 * 256) = a11;
            #pragma unroll
            for (int r = 0; r < 4; r++) {
                int li0 = ti * 32 + crow + r, li1 = li0 + 16;
                int lj0 = tj * 32 + lr,       lj1 = lj0 + 16;
                if (li0 < n && lj0 < n) gsum += a00[r];
                if (li0 < n && lj1 < n) gsum += a01[r];
                if (li1 < n && lj0 < n) gsum += a10[r];
                if (li1 < n && lj1 < n) gsum += a11[r];
            }
            double gs = (double)gsum;
            for (int o = 32; o; o >>= 1) gs += __shfl_down(gs, o);
            if (lane == 0) atomicAdd(&gramsum[c], gs);
        }
    }
    gbar(bars + 2);

    // ---- Phase E: bandwidths into LDS (l2sum = 2n*sum(sq) - 2*gramsum) ----
    for (int c = w; c < C; c += 8) {
        int bs = roS[c], en = roS[c + 1], n = en - bs;
        double s = 0.0;
        for (int i = bs + lane; i < en; i += 64) s += (double)sqg[i];
        for (int o = 32; o; o >>= 1) s += __shfl_down(s, o);
        if (lane == 0) {
            double l2 = 2.0 * (double)n * s - 2.0 * gramsum[c];
            double den = (double)n * (double)n - (double)n; if (den < 1.0) den = 1.0;
            double bw = l2 / den / 4.0;     // bw_scale = 4
            bw = presS[c] ? fmax(bw, 1e-20) : 1.0;
            double m = 1.0;
            for (int k = 0; k < 5; k++) { invbwS[c * 5 + k] = (float)(1.0 / (bw * m)); m *= 2.0; }
        }
    }
    __syncthreads();

    // ---- Phase F: epilogue (sum K-slices, exp kernels, sign, per-class sum) ----
    {
        int nTiles = nTilesS;
        int kgrp = lane >> 4, lr = lane & 15, crow = (lane >> 4) * 4;
        for (int tile = b * 8 + w; tile < nTiles; tile += NWAVES) {
            int c = __popcll(__ballot((lane < C) && (tpoS[lane] <= tile))) - 1;
            int t = tile - tpoS[c];
            int T = tS[c];
            int ti = t / T, tj = t - ti * T;
            int base = roS[c];
            int n = roS[c + 1] - base;

            f32x4 a00, a01, a10, a11;
            if (tile < capTiles) {
                const float* Pb = Pbuf + (size_t)tile * 4096 + lane * 4;
                a00 = (f32x4){0.f, 0.f, 0.f, 0.f}; a01 = a00; a10 = a00; a11 = a00;
                #pragma unroll
                for (int kc = 0; kc < 4; kc++) {
                    a00 += *(const f32x4*)(Pb + kc * 1024 + 0 * 256);
                    a01 += *(const f32x4*)(Pb + kc * 1024 + 1 * 256);
                    a10 += *(const f32x4*)(Pb + kc * 1024 + 2 * 256);
                    a11 += *(const f32x4*)(Pb + kc * 1024 + 3 * 256);
                }
            } else {   // fallback: recompute full-K dot (only if Pbuf capacity exceeded)
                int riA0 = min(ti * 32 + lr, n - 1), riA1 = min(ti * 32 + lr + 16, n - 1);
                int riB0 = min(tj * 32 + lr, n - 1), riB1 = min(tj * 32 + lr + 16, n - 1);
                const unsigned short* pA0 = Xg + (size_t)(base + riA0) * D + kgrp * 8;
                const unsigned short* pA1 = Xg + (size_t)(base + riA1) * D + kgrp * 8;
                const unsigned short* pB0 = Xg + (size_t)(base + riB0) * D + kgrp * 8;
                const unsigned short* pB1 = Xg + (size_t)(base + riB1) * D + kgrp * 8;
                a00 = (f32x4){0.f, 0.f, 0.f, 0.f}; a01 = a00; a10 = a00; a11 = a00;
                for (int k0 = 0; k0 < D; k0 += 32) {
                    bf16x8 va0 = *(const bf16x8*)(pA0 + k0);
                    bf16x8 va1 = *(const bf16x8*)(pA1 + k0);
                    bf16x8 vb0 = *(const bf16x8*)(pB0 + k0);
                    bf16x8 vb1 = *(const bf16x8*)(pB1 + k0);
                    a00 = __builtin_amdgcn_mfma_f32_16x16x32_bf16(va0, vb0, a00, 0, 0, 0);
                    a01 = __builtin_amdgcn_mfma_f32_16x16x32_bf16(va0, vb1, a01, 0, 0, 0);
                    a10 = __builtin_amdgcn_mfma_f32_16x16x32_bf16(va1, vb0, a10, 0, 0, 0);
                    a11 = __builtin_amdgcn_mfma_f32_16x16x32_bf16(va1, vb1, a11, 0, 0, 0);
                }
            }

            float ib0 = invbwS[c * 5 + 0], ib1 = invbwS[c * 5 + 1], ib2 = invbwS[c * 5 + 2];
            float ib3 = invbwS[c * 5 + 3], ib4 = invbwS[c * 5 + 4];
            int lj0 = tj * 32 + lr, lj1 = lj0 + 16;
            float sB0 = sqg[base + min(lj0, n - 1)], gB0 = sgg[base + min(lj0, n - 1)];
            float sB1 = sqg[base + min(lj1, n - 1)], gB1 = sgg[base + min(lj1, n - 1)];
            float tsum = 0.f;
            #pragma unroll
            for (int r = 0; r < 4; r++) {
                int li0 = ti * 32 + crow + r, li1 = li0 + 16;
                float sA0 = sqg[base + min(li0, n - 1)], gA0 = sgg[base + min(li0, n - 1)];
                float sA1 = sqg[base + min(li1, n - 1)], gA1 = sgg[base + min(li1, n - 1)];
                if (li0 < n && lj0 < n) {
                    float D2 = sA0 + sB0 - 2.f * a00[r];
                    tsum += gA0 * gB0 * (expf(-D2 * ib0) + expf(-D2 * ib1) + expf(-D2 * ib2)
                                       + expf(-D2 * ib3) + expf(-D2 * ib4));
                }
                if (li0 < n && lj1 < n) {
                    float D2 = sA0 + sB1 - 2.f * a01[r];
                    tsum += gA0 * gB1 * (expf(-D2 * ib0) + expf(-D2 * ib1) + expf(-D2 * ib2)
                                       + expf(-D2 * ib3) + expf(-D2 * ib4));
                }
                if (li1 < n && lj0 < n) {
                    float D2 = sA1 + sB0 - 2.f * a10[r];
                    tsum += gA1 * gB0 * (expf(-D2 * ib0) + expf(-D2 * ib1) + expf(-D2 * ib2)
                                       + expf(-D2 * ib3) + expf(-D2 * ib4));
                }
                if (li1 < n && lj1 < n) {
                    float D2 = sA1 + sB1 - 2.f * a11[r];
                    tsum += gA1 * gB1 * (expf(-D2 * ib0) + expf(-D2 * ib1) + expf(-D2 * ib2)
                                       + expf(-D2 * ib3) + expf(-D2 * ib4));
                }
            }
            double ds = (double)tsum;
            for (int o = 32; o; o >>= 1) ds += __shfl_down(ds, o);
            if (lane == 0) atomicAdd(&contrib[c], ds);
        }
    }
    gbar(bars + 3);

    // ---- Phase G: final reduction (block 0, wave 0) ----
    if (b == 0 && w == 0) {
        double l = 0.0, k = 0.0;
        if (lane < C && presS[lane]) { l = contrib[lane] * inv_n2S[lane]; k = 1.0; }
        for (int o = 32; o; o >>= 1) { l += __shfl_down(l, o); k += __shfl_down(k, o); }
        if (lane == 0) out[0] = (float)(l / k);
    }
}

extern "C" void kernel_launch(void* const* d_in, const int* in_sizes, int n_in,
                              void* d_out, int out_size, void* d_ws, size_t ws_size,
                              hipStream_t stream) {
    const float* src  = (const float*)d_in[0];
    const float* tgt  = (const float*)d_in[1];
    const int*   slab = (const int*)d_in[2];
    const float* tlab = (const float*)d_in[3];
    const int ns = in_sizes[2];
    const int D  = in_sizes[0] / ns;
    const int nt = in_sizes[1] / D;
    const int C  = in_sizes[3] / nt;
    const int N  = ns + nt;

    char* w = (char*)d_ws;
    size_t off = 0;
    auto take = [&](size_t bytes) -> char* {
        char* p = w + off;
        off = (off + bytes + 255) & ~(size_t)255;
        return p;
    };
    // --- zero region (memset below) ---
    int*      cnt_src = (int*)take(32 * sizeof(int));
    int*      fill    = (int*)take(32 * sizeof(int));
    unsigned* bars    = (unsigned*)take(8 * sizeof(unsigned));
    double*   gramsum = (double*)take(32 * sizeof(double));
    double*   contrib = (double*)take(32 * sizeof(double));
    size_t zbytes = off;
    // --- rest ---
    int*            clsrows = (int*)take((size_t)C * N * sizeof(int));
    float*          sqg     = (float*)take((size_t)N * sizeof(float));
    float*          sgg     = (float*)take((size_t)N * sizeof(float));
    unsigned short* Xg      = (unsigned short*)take((size_t)N * D * sizeof(unsigned short));
    size_t remain = (ws_size > off) ? (ws_size - off) : 0;
    long long capLL = (long long)(remain / (4096ull * sizeof(float)));
    int capTiles = (int)((capLL > 65536) ? 65536 : capLL);
    float* Pbuf = (float*)(w + off);
    (void)n_in; (void)out_size;

    hipMemsetAsync(d_ws, 0, zbytes, stream);
    k_all<<<NBLK, NTHR, 0, stream>>>(src, tgt, slab, tlab, ns, N, D, C,
                                     clsrows, cnt_src, fill, bars, gramsum, contrib,
                                     Xg, sqg, sgg, Pbuf, capTiles, (float*)d_out);
}

// Round 8
// 320.598 us; speedup vs baseline: 1.4629x; 1.4629x over previous
//
#include <hip/hip_runtime.h>

typedef __attribute__((ext_vector_type(8))) short bf16x8;
typedef __attribute__((ext_vector_type(4))) float f32x4;

#define NBLK 512
#define NTHR 512
#define NWAVES (NBLK * 8)

__device__ __forceinline__ unsigned f2bf(float x) {
    unsigned u = __float_as_uint(x);
    return (u + 0x7fffu + ((u >> 16) & 1u)) >> 16;   // RNE f32->bf16
}

// device-scope grid barrier; all NBLK blocks guaranteed co-resident.
// Spin uses RELAXED load (no per-iteration buffer_inv L2-invalidate storm);
// one release fence at arrival + one acquire fence at exit.
__device__ __forceinline__ void gbar(unsigned* bar) {
    __syncthreads();
    if (threadIdx.x == 0) {
        __threadfence();                               // release prior writes (agent)
        atomicAdd(bar, 1u);                            // relaxed RMW
        while (__hip_atomic_load(bar, __ATOMIC_RELAXED, __HIP_MEMORY_SCOPE_AGENT) < NBLK)
            __builtin_amdgcn_s_sleep(16);
        __threadfence();                               // acquire remote writes
    }
    __syncthreads();
}

__global__ __launch_bounds__(NTHR, 4) void k_all(
        const float* __restrict__ src, const float* __restrict__ tgt,
        const int* __restrict__ slab, const float* __restrict__ tlab,
        int ns, int N, int D, int C,
        int* __restrict__ clsrows, int* __restrict__ cnt_src, int* __restrict__ fill,
        unsigned* __restrict__ bars, double* __restrict__ gramsum,
        double* __restrict__ contrib,
        unsigned short* __restrict__ Xg, float* __restrict__ sqg, float* __restrict__ sgg,
        float* __restrict__ Pbuf, int capTiles, float* __restrict__ out) {
    const int tid = threadIdx.x;
    const int lane = tid & 63;
    const int w = tid >> 6;            // wave 0..7
    const int b = blockIdx.x;

    __shared__ int roS[33], tpoS[33], tS[32], presS[32];
    __shared__ float invbwS[32 * 5];
    __shared__ double inv_n2S[32];
    __shared__ int nTilesS;

    // ---- Phase A: labels (argmax for target), class counts, row lists ----
    for (int i = b * 8 + w; i < N; i += NWAVES) {
        int lab;
        if (i < ns) {
            lab = slab[i];
        } else {
            float v = -3.4e38f; int idx = C;
            if (lane < C) { v = tlab[(size_t)(i - ns) * C + lane]; idx = lane; }
            for (int o = 32; o; o >>= 1) {
                float v2 = __shfl_xor(v, o);
                int i2 = __shfl_xor(idx, o);
                if (v2 > v || (v2 == v && i2 < idx)) { v = v2; idx = i2; }  // first-max
            }
            lab = idx;
        }
        if (lane == 0) {
            if (i < ns) atomicAdd(&cnt_src[lab], 1);
            int pos = atomicAdd(&fill[lab], 1);
            clsrows[(size_t)lab * N + pos] = i;
        }
    }
    gbar(bars + 0);

    // ---- Phase B: per-block offsets into LDS (wave 0) ----
    if (w == 0) {
        int n = (lane < C) ? fill[lane] : 0;
        int nsrc = (lane < C) ? cnt_src[lane] : 0;
        int pres = (nsrc > 0 && (n - nsrc) > 0) ? 1 : 0;
        int T = pres ? (n + 31) / 32 : 0;
        int t2 = T * T;
        int sn = n, sp = t2;
        for (int o = 1; o < 64; o <<= 1) {
            int a = __shfl_up(sn, o), c2 = __shfl_up(sp, o);
            if (lane >= o) { sn += a; sp += c2; }
        }
        if (lane < C) {
            roS[lane] = sn - n; tpoS[lane] = sp - t2;
            tS[lane] = T; presS[lane] = pres;
            double nn = (double)n * (double)n; if (nn < 1.0) nn = 1.0;
            inv_n2S[lane] = 1.0 / nn;
        }
        if (lane == C - 1) { roS[C] = sn; tpoS[C] = sp; nTilesS = sp; }
    }
    __syncthreads();

    // ---- Phase C: gather rows class-contiguously as bf16; sq + sign ----
    for (int s = b * 8 + w; s < N; s += NWAVES) {
        int c = __popcll(__ballot((lane < C) && (roS[lane] <= s))) - 1;
        int g = clsrows[(size_t)c * N + (s - roS[c])];
        const float* row = (g < ns) ? src + (size_t)g * D : tgt + (size_t)(g - ns) * D;
        unsigned short* orow = Xg + (size_t)s * D;
        float acc = 0.f;
        for (int it = 0; it < D / 256; ++it) {
            float4 v = *(const float4*)(row + it * 256 + lane * 4);
            acc += v.x * v.x + v.y * v.y + v.z * v.z + v.w * v.w;
            uint2 p;
            p.x = f2bf(v.x) | (f2bf(v.y) << 16);
            p.y = f2bf(v.z) | (f2bf(v.w) << 16);
            *(uint2*)(orow + it * 256 + lane * 4) = p;
        }
        for (int o = 32; o; o >>= 1) acc += __shfl_down(acc, o);
        if (lane == 0) { sqg[s] = acc; sgg[s] = (g < ns) ? 1.f : -1.f; }
    }
    gbar(bars + 1);

    // ---- Phase D: split-K pair dots (MFMA) + per-class gram-sum ----
    {
        int nTiles = nTilesS;
        int nJobsK = nTiles * 4;
        int KC = D / 4;
        int kgrp = lane >> 4, lr = lane & 15, crow = (lane >> 4) * 4;
        for (int j = b * 8 + w; j < nJobsK; j += NWAVES) {
            int kc = j / nTiles;
            int tile = j - kc * nTiles;
            int c = __popcll(__ballot((lane < C) && (tpoS[lane] <= tile))) - 1;
            int t = tile - tpoS[c];
            int T = tS[c];
            int ti = t / T, tj = t - ti * T;
            int base = roS[c];
            int n = roS[c + 1] - base;

            int riA0 = min(ti * 32 + lr, n - 1), riA1 = min(ti * 32 + lr + 16, n - 1);
            int riB0 = min(tj * 32 + lr, n - 1), riB1 = min(tj * 32 + lr + 16, n - 1);
            const unsigned short* pA0 = Xg + (size_t)(base + riA0) * D + kc * KC + kgrp * 8;
            const unsigned short* pA1 = Xg + (size_t)(base + riA1) * D + kc * KC + kgrp * 8;
            const unsigned short* pB0 = Xg + (size_t)(base + riB0) * D + kc * KC + kgrp * 8;
            const unsigned short* pB1 = Xg + (size_t)(base + riB1) * D + kc * KC + kgrp * 8;

            f32x4 a00 = (f32x4){0.f, 0.f, 0.f, 0.f}, a01 = a00, a10 = a00, a11 = a00;
            #pragma unroll 4
            for (int k0 = 0; k0 < KC; k0 += 32) {
                bf16x8 va0 = *(const bf16x8*)(pA0 + k0);
                bf16x8 va1 = *(const bf16x8*)(pA1 + k0);
                bf16x8 vb0 = *(const bf16x8*)(pB0 + k0);
                bf16x8 vb1 = *(const bf16x8*)(pB1 + k0);
                a00 = __builtin_amdgcn_mfma_f32_16x16x32_bf16(va0, vb0, a00, 0, 0, 0);
                a01 = __builtin_amdgcn_mfma_f32_16x16x32_bf16(va0, vb1, a01, 0, 0, 0);
                a10 = __builtin_amdgcn_mfma_f32_16x16x32_bf16(va1, vb0, a10, 0, 0, 0);
                a11 = __builtin_amdgcn_mfma_f32_16x16x32_bf16(va1, vb1, a11, 0, 0, 0);
            }

            float gsum = 0.f;
            float* Pb = Pbuf + ((size_t)tile * 4 + kc) * 1024 + lane * 4;
            bool store = (tile < capTiles);
            // frag (fi,fj): rows ti*32+fi*16+crow+r, cols tj*32+fj*16+lr  [m89 layout]
            if (store) *(f32x4*)(Pb + 0 * 256) = a00;
            if (store) *(f32x4*)(Pb + 1 * 256) = a01;
            if (store) *(f32x4*)(Pb + 2 * 256) = a10;
            if (store) *(f32x4*)(Pb + 3 * 256) = a11;
            #pragma unroll
            for (int r = 0; r < 4; r++) {
                int li0 = ti * 32 + crow + r, li1 = li0 + 16;
                int lj0 = tj * 32 + lr,       lj1 = lj0 + 16;
                if (li0 < n && lj0 < n) gsum += a00[r];
                if (li0 < n && lj1 < n) gsum += a01[r];
                if (li1 < n && lj0 < n) gsum += a10[r];
                if (li1 < n && lj1 < n) gsum += a11[r];
            }
            double gs = (double)gsum;
            for (int o = 32; o; o >>= 1) gs += __shfl_down(gs, o);
            if (lane == 0) atomicAdd(&gramsum[c], gs);
        }
    }
    gbar(bars + 2);

    // ---- Phase E: bandwidths into LDS (l2sum = 2n*sum(sq) - 2*gramsum) ----
    for (int c = w; c < C; c += 8) {
        int bs = roS[c], en = roS[c + 1], n = en - bs;
        double s = 0.0;
        for (int i = bs + lane; i < en; i += 64) s += (double)sqg[i];
        for (int o = 32; o; o >>= 1) s += __shfl_down(s, o);
        if (lane == 0) {
            double l2 = 2.0 * (double)n * s - 2.0 * gramsum[c];
            double den = (double)n * (double)n - (double)n; if (den < 1.0) den = 1.0;
            double bw = l2 / den / 4.0;     // bw_scale = 4
            bw = presS[c] ? fmax(bw, 1e-20) : 1.0;
            double m = 1.0;
            for (int k = 0; k < 5; k++) { invbwS[c * 5 + k] = (float)(1.0 / (bw * m)); m *= 2.0; }
        }
    }
    __syncthreads();

    // ---- Phase F: epilogue (sum K-slices, exp kernels, sign, per-class sum) ----
    {
        int nTiles = nTilesS;
        int kgrp = lane >> 4, lr = lane & 15, crow = (lane >> 4) * 4;
        for (int tile = b * 8 + w; tile < nTiles; tile += NWAVES) {
            int c = __popcll(__ballot((lane < C) && (tpoS[lane] <= tile))) - 1;
            int t = tile - tpoS[c];
            int T = tS[c];
            int ti = t / T, tj = t - ti * T;
            int base = roS[c];
            int n = roS[c + 1] - base;

            f32x4 a00, a01, a10, a11;
            if (tile < capTiles) {
                const float* Pb = Pbuf + (size_t)tile * 4096 + lane * 4;
                a00 = (f32x4){0.f, 0.f, 0.f, 0.f}; a01 = a00; a10 = a00; a11 = a00;
                #pragma unroll
                for (int kc = 0; kc < 4; kc++) {
                    a00 += *(const f32x4*)(Pb + kc * 1024 + 0 * 256);
                    a01 += *(const f32x4*)(Pb + kc * 1024 + 1 * 256);
                    a10 += *(const f32x4*)(Pb + kc * 1024 + 2 * 256);
                    a11 += *(const f32x4*)(Pb + kc * 1024 + 3 * 256);
                }
            } else {   // fallback: recompute full-K dot (only if Pbuf capacity exceeded)
                int riA0 = min(ti * 32 + lr, n - 1), riA1 = min(ti * 32 + lr + 16, n - 1);
                int riB0 = min(tj * 32 + lr, n - 1), riB1 = min(tj * 32 + lr + 16, n - 1);
                const unsigned short* pA0 = Xg + (size_t)(base + riA0) * D + kgrp * 8;
                const unsigned short* pA1 = Xg + (size_t)(base + riA1) * D + kgrp * 8;
                const unsigned short* pB0 = Xg + (size_t)(base + riB0) * D + kgrp * 8;
                const unsigned short* pB1 = Xg + (size_t)(base + riB1) * D + kgrp * 8;
                a00 = (f32x4){0.f, 0.f, 0.f, 0.f}; a01 = a00; a10 = a00; a11 = a00;
                for (int k0 = 0; k0 < D; k0 += 32) {
                    bf16x8 va0 = *(const bf16x8*)(pA0 + k0);
                    bf16x8 va1 = *(const bf16x8*)(pA1 + k0);
                    bf16x8 vb0 = *(const bf16x8*)(pB0 + k0);
                    bf16x8 vb1 = *(const bf16x8*)(pB1 + k0);
                    a00 = __builtin_amdgcn_mfma_f32_16x16x32_bf16(va0, vb0, a00, 0, 0, 0);
                    a01 = __builtin_amdgcn_mfma_f32_16x16x32_bf16(va0, vb1, a01, 0, 0, 0);
                    a10 = __builtin_amdgcn_mfma_f32_16x16x32_bf16(va1, vb0, a10, 0, 0, 0);
                    a11 = __builtin_amdgcn_mfma_f32_16x16x32_bf16(va1, vb1, a11, 0, 0, 0);
                }
            }

            float ib0 = invbwS[c * 5 + 0], ib1 = invbwS[c * 5 + 1], ib2 = invbwS[c * 5 + 2];
            float ib3 = invbwS[c * 5 + 3], ib4 = invbwS[c * 5 + 4];
            int lj0 = tj * 32 + lr, lj1 = lj0 + 16;
            float sB0 = sqg[base + min(lj0, n - 1)], gB0 = sgg[base + min(lj0, n - 1)];
            float sB1 = sqg[base + min(lj1, n - 1)], gB1 = sgg[base + min(lj1, n - 1)];
            float tsum = 0.f;
            #pragma unroll
            for (int r = 0; r < 4; r++) {
                int li0 = ti * 32 + crow + r, li1 = li0 + 16;
                float sA0 = sqg[base + min(li0, n - 1)], gA0 = sgg[base + min(li0, n - 1)];
                float sA1 = sqg[base + min(li1, n - 1)], gA1 = sgg[base + min(li1, n - 1)];
                if (li0 < n && lj0 < n) {
                    float D2 = sA0 + sB0 - 2.f * a00[r];
                    tsum += gA0 * gB0 * (expf(-D2 * ib0) + expf(-D2 * ib1) + expf(-D2 * ib2)
                                       + expf(-D2 * ib3) + expf(-D2 * ib4));
                }
                if (li0 < n && lj1 < n) {
                    float D2 = sA0 + sB1 - 2.f * a01[r];
                    tsum += gA0 * gB1 * (expf(-D2 * ib0) + expf(-D2 * ib1) + expf(-D2 * ib2)
                                       + expf(-D2 * ib3) + expf(-D2 * ib4));
                }
                if (li1 < n && lj0 < n) {
                    float D2 = sA1 + sB0 - 2.f * a10[r];
                    tsum += gA1 * gB0 * (expf(-D2 * ib0) + expf(-D2 * ib1) + expf(-D2 * ib2)
                                       + expf(-D2 * ib3) + expf(-D2 * ib4));
                }
                if (li1 < n && lj1 < n) {
                    float D2 = sA1 + sB1 - 2.f * a11[r];
                    tsum += gA1 * gB1 * (expf(-D2 * ib0) + expf(-D2 * ib1) + expf(-D2 * ib2)
                                       + expf(-D2 * ib3) + expf(-D2 * ib4));
                }
            }
            double ds = (double)tsum;
            for (int o = 32; o; o >>= 1) ds += __shfl_down(ds, o);
            if (lane == 0) atomicAdd(&contrib[c], ds);
        }
    }
    gbar(bars + 3);

    // ---- Phase G: final reduction (block 0, wave 0) ----
    if (b == 0 && w == 0) {
        double l = 0.0, k = 0.0;
        if (lane < C && presS[lane]) { l = contrib[lane] * inv_n2S[lane]; k = 1.0; }
        for (int o = 32; o; o >>= 1) { l += __shfl_down(l, o); k += __shfl_down(k, o); }
        if (lane == 0) out[0] = (float)(l / k);
    }
}

extern "C" void kernel_launch(void* const* d_in, const int* in_sizes, int n_in,
                              void* d_out, int out_size, void* d_ws, size_t ws_size,
                              hipStream_t stream) {
    const float* src  = (const float*)d_in[0];
    const float* tgt  = (const float*)d_in[1];
    const int*   slab = (const int*)d_in[2];
    const float* tlab = (const float*)d_in[3];
    const int ns = in_sizes[2];
    const int D  = in_sizes[0] / ns;
    const int nt = in_sizes[1] / D;
    const int C  = in_sizes[3] / nt;
    const int N  = ns + nt;

    char* w = (char*)d_ws;
    size_t off = 0;
    auto take = [&](size_t bytes) -> char* {
        char* p = w + off;
        off = (off + bytes + 255) & ~(size_t)255;
        return p;
    };
    // --- zero region (memset below) ---
    int*      cnt_src = (int*)take(32 * sizeof(int));
    int*      fill    = (int*)take(32 * sizeof(int));
    unsigned* bars    = (unsigned*)take(8 * sizeof(unsigned));
    double*   gramsum = (double*)take(32 * sizeof(double));
    double*   contrib = (double*)take(32 * sizeof(double));
    size_t zbytes = off;
    // --- rest ---
    int*            clsrows = (int*)take((size_t)C * N * sizeof(int));
    float*          sqg     = (float*)take((size_t)N * sizeof(float));
    float*          sgg     = (float*)take((size_t)N * sizeof(float));
    unsigned short* Xg      = (unsigned short*)take((size_t)N * D * sizeof(unsigned short));
    size_t remain = (ws_size > off) ? (ws_size - off) : 0;
    long long capLL = (long long)(remain / (4096ull * sizeof(float)));
    int capTiles = (int)((capLL > 65536) ? 65536 : capLL);
    float* Pbuf = (float*)(w + off);
    (void)n_in; (void)out_size;

    hipMemsetAsync(d_ws, 0, zbytes, stream);
    k_all<<<NBLK, NTHR, 0, stream>>>(src, tgt, slab, tlab, ns, N, D, C,
                                     clsrows, cnt_src, fill, bars, gramsum, contrib,
                                     Xg, sqg, sgg, Pbuf, capTiles, (float*)d_out);
}

// Round 9
// 160.276 us; speedup vs baseline: 2.9262x; 2.0003x over previous
//
#include <hip/hip_runtime.h>

typedef __attribute__((ext_vector_type(8))) short bf16x8;
typedef __attribute__((ext_vector_type(4))) float f32x4;

#define TILE 32

__device__ __forceinline__ unsigned f2bf(float x) {
    unsigned u = __float_as_uint(x);
    return (u + 0x7fffu + ((u >> 16) & 1u)) >> 16;   // RNE f32->bf16
}

// ---- labels: t_hard = argmax(t_label); per-class counts + row lists ----
__global__ void k_prep(const int* __restrict__ slab, const float* __restrict__ tlab,
                       int ns, int N, int C,
                       int* __restrict__ clsrows, int* __restrict__ cnt_src,
                       int* __restrict__ fill) {
    int i = blockIdx.x * 256 + threadIdx.x;
    if (i >= N) return;
    int lab;
    if (i < ns) {
        lab = slab[i];
    } else {
        const float* row = tlab + (size_t)(i - ns) * C;
        float best = row[0];
        lab = 0;
        for (int c = 1; c < C; c++) {
            float v = row[c];
            if (v > best) { best = v; lab = c; }   // strict >: first-max (jnp.argmax)
        }
    }
    if (i < ns) atomicAdd(&cnt_src[lab], 1);
    int pos = atomicAdd(&fill[lab], 1);
    clsrows[(size_t)lab * N + pos] = i;
}

// per-block redundant class-offset scan into LDS (wave 0 of the block)
__device__ __forceinline__ void scan_offsets(const int* __restrict__ cnt_src,
                                             const int* __restrict__ fill, int C,
                                             int* roS, int* tpoS, int* tS, int* presS,
                                             int* nTilesS) {
    if (threadIdx.x < 64) {
        int lane = threadIdx.x;
        int n = (lane < C) ? fill[lane] : 0;
        int nsrc = (lane < C) ? cnt_src[lane] : 0;
        int pres = (nsrc > 0 && (n - nsrc) > 0) ? 1 : 0;
        int T = pres ? (n + TILE - 1) / TILE : 0;
        int t2 = T * T;
        int sn = n, sp = t2;
        for (int o = 1; o < 64; o <<= 1) {
            int a = __shfl_up(sn, o), b2 = __shfl_up(sp, o);
            if (lane >= o) { sn += a; sp += b2; }
        }
        if (lane < C) {
            roS[lane] = sn - n; tpoS[lane] = sp - t2;
            tS[lane] = T; presS[lane] = pres;
        }
        if (lane == C - 1) { roS[C] = sn; tpoS[C] = sp; *nTilesS = sp; }
    }
    __syncthreads();
}

// ---- gather rows class-contiguously as bf16; sq (f32), sign, sqsum[c] ----
__global__ __launch_bounds__(256) void k_gather(
        const float* __restrict__ src, const float* __restrict__ tgt,
        const int* __restrict__ clsrows, const int* __restrict__ cnt_src,
        const int* __restrict__ fill,
        int ns, int N, int D, int C,
        unsigned short* __restrict__ Xg, float* __restrict__ sqg, float* __restrict__ sgg,
        double* __restrict__ sqsum) {
    __shared__ int roS[33], tpoS[33], tS[32], presS[32], nTilesS;
    scan_offsets(cnt_src, fill, C, roS, tpoS, tS, presS, &nTilesS);

    int s = blockIdx.x;
    int tid = threadIdx.x;
    int lane = tid & 63;
    int c = __popcll(__ballot((lane < C) && (roS[lane] <= s))) - 1;
    int g = clsrows[(size_t)c * N + (s - roS[c])];
    const float* row = (g < ns) ? src + (size_t)g * D : tgt + (size_t)(g - ns) * D;
    unsigned int* orow = (unsigned int*)(Xg + (size_t)s * D);
    float acc = 0.f;
    for (int it = 0; it < D / 512; it++) {
        float2 v = *(const float2*)(row + it * 512 + tid * 2);
        acc += v.x * v.x + v.y * v.y;
        orow[it * 256 + tid] = f2bf(v.x) | (f2bf(v.y) << 16);
    }
    for (int o = 32; o; o >>= 1) acc += __shfl_down(acc, o);
    __shared__ float ls[4];
    if ((tid & 63) == 0) ls[tid >> 6] = acc;
    __syncthreads();
    if (tid == 0) {
        float tot = ls[0] + ls[1] + ls[2] + ls[3];
        sqg[s] = tot;
        sgg[s] = (g < ns) ? 1.f : -1.f;
        atomicAdd(&sqsum[c], (double)tot);
    }
}

// ---- split-K pair dots (MFMA): partials -> Pbuf, masked gram-sum -> gramsum ----
__global__ __launch_bounds__(256) void k_pairs(
        const unsigned short* __restrict__ Xg,
        const int* __restrict__ cnt_src, const int* __restrict__ fill,
        int ns, int N, int D, int C,
        float* __restrict__ Pbuf, int capTiles, double* __restrict__ gramsum) {
    __shared__ int roS[33], tpoS[33], tS[32], presS[32], nTilesS;
    scan_offsets(cnt_src, fill, C, roS, tpoS, tS, presS, &nTilesS);

    int tid = threadIdx.x;
    int lane = tid & 63;
    int w = tid >> 6;
    int nTiles = nTilesS;
    int nJobsK = nTiles * 4;
    int KC = D / 4;
    int kgrp = lane >> 4, lr = lane & 15, crow = (lane >> 4) * 4;
    int gw = blockIdx.x * 4 + w;
    int nW = gridDim.x * 4;

    for (int j = gw; j < nJobsK; j += nW) {
        int kc = j / nTiles;
        int tile = j - kc * nTiles;
        int c = __popcll(__ballot((lane < C) && (tpoS[lane] <= tile))) - 1;
        int t = tile - tpoS[c];
        int T = tS[c];
        int ti = t / T, tj = t - ti * T;
        int base = roS[c];
        int n = roS[c + 1] - base;

        int riA0 = min(ti * 32 + lr, n - 1), riA1 = min(ti * 32 + lr + 16, n - 1);
        int riB0 = min(tj * 32 + lr, n - 1), riB1 = min(tj * 32 + lr + 16, n - 1);
        const unsigned short* pA0 = Xg + (size_t)(base + riA0) * D + kc * KC + kgrp * 8;
        const unsigned short* pA1 = Xg + (size_t)(base + riA1) * D + kc * KC + kgrp * 8;
        const unsigned short* pB0 = Xg + (size_t)(base + riB0) * D + kc * KC + kgrp * 8;
        const unsigned short* pB1 = Xg + (size_t)(base + riB1) * D + kc * KC + kgrp * 8;

        f32x4 a00 = (f32x4){0.f, 0.f, 0.f, 0.f}, a01 = a00, a10 = a00, a11 = a00;
        #pragma unroll 4
        for (int k0 = 0; k0 < KC; k0 += 32) {
            bf16x8 va0 = *(const bf16x8*)(pA0 + k0);
            bf16x8 va1 = *(const bf16x8*)(pA1 + k0);
            bf16x8 vb0 = *(const bf16x8*)(pB0 + k0);
            bf16x8 vb1 = *(const bf16x8*)(pB1 + k0);
            a00 = __builtin_amdgcn_mfma_f32_16x16x32_bf16(va0, vb0, a00, 0, 0, 0);
            a01 = __builtin_amdgcn_mfma_f32_16x16x32_bf16(va0, vb1, a01, 0, 0, 0);
            a10 = __builtin_amdgcn_mfma_f32_16x16x32_bf16(va1, vb0, a10, 0, 0, 0);
            a11 = __builtin_amdgcn_mfma_f32_16x16x32_bf16(va1, vb1, a11, 0, 0, 0);
        }

        // frag (fi,fj): rows ti*32+fi*16+crow+r, cols tj*32+fj*16+lr  [m89 layout]
        if (tile < capTiles) {
            float* Pb = Pbuf + ((size_t)tile * 4 + kc) * 1024 + lane * 4;
            *(f32x4*)(Pb + 0 * 256) = a00;
            *(f32x4*)(Pb + 1 * 256) = a01;
            *(f32x4*)(Pb + 2 * 256) = a10;
            *(f32x4*)(Pb + 3 * 256) = a11;
        }
        float gsum = 0.f;
        #pragma unroll
        for (int r = 0; r < 4; r++) {
            int li0 = ti * 32 + crow + r, li1 = li0 + 16;
            int lj0 = tj * 32 + lr,       lj1 = lj0 + 16;
            if (li0 < n && lj0 < n) gsum += a00[r];
            if (li0 < n && lj1 < n) gsum += a01[r];
            if (li1 < n && lj0 < n) gsum += a10[r];
            if (li1 < n && lj1 < n) gsum += a11[r];
        }
        double gs = (double)gsum;
        for (int o = 32; o; o >>= 1) gs += __shfl_down(gs, o);
        if (lane == 0) atomicAdd(&gramsum[c], gs);
    }
}

// ---- epilogue: per-block bw from sqsum/gramsum; sum K-slices; exp; contrib ----
__global__ __launch_bounds__(256) void k_epi(
        const unsigned short* __restrict__ Xg, const float* __restrict__ sqg,
        const float* __restrict__ sgg,
        const int* __restrict__ cnt_src, const int* __restrict__ fill,
        const double* __restrict__ sqsum, const double* __restrict__ gramsum,
        int ns, int N, int D, int C,
        const float* __restrict__ Pbuf, int capTiles, double* __restrict__ contrib) {
    __shared__ int roS[33], tpoS[33], tS[32], presS[32], nTilesS;
    __shared__ float invbwS[32 * 5];
    scan_offsets(cnt_src, fill, C, roS, tpoS, tS, presS, &nTilesS);
    if (threadIdx.x < 64) {
        int lane = threadIdx.x;
        if (lane < C) {
            int n = roS[lane + 1] - roS[lane];
            double l2 = 2.0 * (double)n * sqsum[lane] - 2.0 * gramsum[lane];
            double den = (double)n * (double)n - (double)n; if (den < 1.0) den = 1.0;
            double bw = l2 / den / 4.0;        // bw_scale = KERNEL_MUL^(KERNEL_NUM//2)
            bw = presS[lane] ? fmax(bw, 1e-20) : 1.0;
            double m = 1.0;
            for (int k = 0; k < 5; k++) { invbwS[lane * 5 + k] = (float)(1.0 / (bw * m)); m *= 2.0; }
        }
    }
    __syncthreads();

    int tid = threadIdx.x;
    int lane = tid & 63;
    int w = tid >> 6;
    int nTiles = nTilesS;
    int kgrp = lane >> 4, lr = lane & 15, crow = (lane >> 4) * 4;
    int gw = blockIdx.x * 4 + w;
    int nW = gridDim.x * 4;

    for (int tile = gw; tile < nTiles; tile += nW) {
        int c = __popcll(__ballot((lane < C) && (tpoS[lane] <= tile))) - 1;
        int t = tile - tpoS[c];
        int T = tS[c];
        int ti = t / T, tj = t - ti * T;
        int base = roS[c];
        int n = roS[c + 1] - base;

        f32x4 a00, a01, a10, a11;
        if (tile < capTiles) {
            const float* Pb = Pbuf + (size_t)tile * 4096 + lane * 4;
            a00 = (f32x4){0.f, 0.f, 0.f, 0.f}; a01 = a00; a10 = a00; a11 = a00;
            #pragma unroll
            for (int kc = 0; kc < 4; kc++) {
                a00 += *(const f32x4*)(Pb + kc * 1024 + 0 * 256);
                a01 += *(const f32x4*)(Pb + kc * 1024 + 1 * 256);
                a10 += *(const f32x4*)(Pb + kc * 1024 + 2 * 256);
                a11 += *(const f32x4*)(Pb + kc * 1024 + 3 * 256);
            }
        } else {   // fallback (workspace too small): recompute full-K dot
            int riA0 = min(ti * 32 + lr, n - 1), riA1 = min(ti * 32 + lr + 16, n - 1);
            int riB0 = min(tj * 32 + lr, n - 1), riB1 = min(tj * 32 + lr + 16, n - 1);
            const unsigned short* pA0 = Xg + (size_t)(base + riA0) * D + kgrp * 8;
            const unsigned short* pA1 = Xg + (size_t)(base + riA1) * D + kgrp * 8;
            const unsigned short* pB0 = Xg + (size_t)(base + riB0) * D + kgrp * 8;
            const unsigned short* pB1 = Xg + (size_t)(base + riB1) * D + kgrp * 8;
            a00 = (f32x4){0.f, 0.f, 0.f, 0.f}; a01 = a00; a10 = a00; a11 = a00;
            for (int k0 = 0; k0 < D; k0 += 32) {
                bf16x8 va0 = *(const bf16x8*)(pA0 + k0);
                bf16x8 va1 = *(const bf16x8*)(pA1 + k0);
                bf16x8 vb0 = *(const bf16x8*)(pB0 + k0);
                bf16x8 vb1 = *(const bf16x8*)(pB1 + k0);
                a00 = __builtin_amdgcn_mfma_f32_16x16x32_bf16(va0, vb0, a00, 0, 0, 0);
                a01 = __builtin_amdgcn_mfma_f32_16x16x32_bf16(va0, vb1, a01, 0, 0, 0);
                a10 = __builtin_amdgcn_mfma_f32_16x16x32_bf16(va1, vb0, a10, 0, 0, 0);
                a11 = __builtin_amdgcn_mfma_f32_16x16x32_bf16(va1, vb1, a11, 0, 0, 0);
            }
        }

        float ib0 = invbwS[c * 5 + 0], ib1 = invbwS[c * 5 + 1], ib2 = invbwS[c * 5 + 2];
        float ib3 = invbwS[c * 5 + 3], ib4 = invbwS[c * 5 + 4];
        int lj0 = tj * 32 + lr, lj1 = lj0 + 16;
        float sB0 = sqg[base + min(lj0, n - 1)], gB0 = sgg[base + min(lj0, n - 1)];
        float sB1 = sqg[base + min(lj1, n - 1)], gB1 = sgg[base + min(lj1, n - 1)];
        float tsum = 0.f;
        #pragma unroll
        for (int r = 0; r < 4; r++) {
            int li0 = ti * 32 + crow + r, li1 = li0 + 16;
            float sA0 = sqg[base + min(li0, n - 1)], gA0 = sgg[base + min(li0, n - 1)];
            float sA1 = sqg[base + min(li1, n - 1)], gA1 = sgg[base + min(li1, n - 1)];
            if (li0 < n && lj0 < n) {
                float D2 = sA0 + sB0 - 2.f * a00[r];
                tsum += gA0 * gB0 * (expf(-D2 * ib0) + expf(-D2 * ib1) + expf(-D2 * ib2)
                                   + expf(-D2 * ib3) + expf(-D2 * ib4));
            }
            if (li0 < n && lj1 < n) {
                float D2 = sA0 + sB1 - 2.f * a01[r];
                tsum += gA0 * gB1 * (expf(-D2 * ib0) + expf(-D2 * ib1) + expf(-D2 * ib2)
                                   + expf(-D2 * ib3) + expf(-D2 * ib4));
            }
            if (li1 < n && lj0 < n) {
                float D2 = sA1 + sB0 - 2.f * a10[r];
                tsum += gA1 * gB0 * (expf(-D2 * ib0) + expf(-D2 * ib1) + expf(-D2 * ib2)
                                   + expf(-D2 * ib3) + expf(-D2 * ib4));
            }
            if (li1 < n && lj1 < n) {
                float D2 = sA1 + sB1 - 2.f * a11[r];
                tsum += gA1 * gB1 * (expf(-D2 * ib0) + expf(-D2 * ib1) + expf(-D2 * ib2)
                                   + expf(-D2 * ib3) + expf(-D2 * ib4));
            }
        }
        double ds = (double)tsum;
        for (int o = 32; o; o >>= 1) ds += __shfl_down(ds, o);
        if (lane == 0) atomicAdd(&contrib[c], ds);
    }
}

__global__ void k_final(const double* __restrict__ contrib,
                        const int* __restrict__ cnt_src, const int* __restrict__ fill,
                        int C, float* __restrict__ out) {
    int c = threadIdx.x;
    double l = 0.0, k = 0.0;
    if (c < C) {
        int n = fill[c], nsrc = cnt_src[c];
        if (nsrc > 0 && (n - nsrc) > 0) {
            double nn = (double)n * (double)n; if (nn < 1.0) nn = 1.0;
            l = contrib[c] / nn; k = 1.0;
        }
    }
    for (int o = 32; o; o >>= 1) { l += __shfl_down(l, o); k += __shfl_down(k, o); }
    if (c == 0) out[0] = (float)(l / k);
}

extern "C" void kernel_launch(void* const* d_in, const int* in_sizes, int n_in,
                              void* d_out, int out_size, void* d_ws, size_t ws_size,
                              hipStream_t stream) {
    const float* src  = (const float*)d_in[0];
    const float* tgt  = (const float*)d_in[1];
    const int*   slab = (const int*)d_in[2];
    const float* tlab = (const float*)d_in[3];
    const int ns = in_sizes[2];
    const int D  = in_sizes[0] / ns;
    const int nt = in_sizes[1] / D;
    const int C  = in_sizes[3] / nt;
    const int N  = ns + nt;

    char* w = (char*)d_ws;
    size_t off = 0;
    auto take = [&](size_t bytes) -> char* {
        char* p = w + off;
        off = (off + bytes + 255) & ~(size_t)255;
        return p;
    };
    // --- zero region (memset below) ---
    int*    cnt_src = (int*)take(32 * sizeof(int));
    int*    fill    = (int*)take(32 * sizeof(int));
    double* sqsum   = (double*)take(32 * sizeof(double));
    double* gramsum = (double*)take(32 * sizeof(double));
    double* contrib = (double*)take(32 * sizeof(double));
    size_t zbytes = off;
    // --- rest ---
    int*            clsrows = (int*)take((size_t)C * N * sizeof(int));
    float*          sqg     = (float*)take((size_t)N * sizeof(float));
    float*          sgg     = (float*)take((size_t)N * sizeof(float));
    unsigned short* Xg      = (unsigned short*)take((size_t)N * D * sizeof(unsigned short));
    size_t remain = (ws_size > off) ? (ws_size - off) : 0;
    long long capLL = (long long)(remain / (4096ull * sizeof(float)));
    int capTiles = (int)((capLL > 65536) ? 65536 : capLL);
    float* Pbuf = (float*)(w + off);
    (void)n_in; (void)out_size;

    hipMemsetAsync(d_ws, 0, zbytes, stream);
    k_prep<<<(N + 255) / 256, 256, 0, stream>>>(slab, tlab, ns, N, C, clsrows, cnt_src, fill);
    k_gather<<<N, 256, 0, stream>>>(src, tgt, clsrows, cnt_src, fill, ns, N, D, C,
                                    Xg, sqg, sgg, sqsum);
    k_pairs<<<1024, 256, 0, stream>>>(Xg, cnt_src, fill, ns, N, D, C,
                                      Pbuf, capTiles, gramsum);
    k_epi<<<1024, 256, 0, stream>>>(Xg, sqg, sgg, cnt_src, fill, sqsum, gramsum,
                                    ns, N, D, C, Pbuf, capTiles, contrib);
    k_final<<<1, 64, 0, stream>>>(contrib, cnt_src, fill, C, (float*)d_out);
}

// Round 10
// 141.989 us; speedup vs baseline: 3.3031x; 1.1288x over previous
//
#include <hip/hip_runtime.h>
#include <limits.h>

typedef __attribute__((ext_vector_type(8))) short bf16x8;
typedef __attribute__((ext_vector_type(4))) float f32x4;

#define TILE 32

__device__ __forceinline__ unsigned f2bf(float x) {
    unsigned u = __float_as_uint(x);
    return (u + 0x7fffu + ((u >> 16) & 1u)) >> 16;   // RNE f32->bf16
}

// ---- labels: t_hard = argmax(t_label); per-class counts + row lists ----
__global__ void k_prep(const int* __restrict__ slab, const float* __restrict__ tlab,
                       int ns, int N, int C,
                       int* __restrict__ clsrows, int* __restrict__ cnt_src,
                       int* __restrict__ fill) {
    int i = blockIdx.x * 256 + threadIdx.x;
    if (i >= N) return;
    int lab;
    if (i < ns) {
        lab = slab[i];
    } else {
        const float* row = tlab + (size_t)(i - ns) * C;
        float best = row[0];
        lab = 0;
        for (int c = 1; c < C; c++) {
            float v = row[c];
            if (v > best) { best = v; lab = c; }   // strict >: first-max (jnp.argmax)
        }
    }
    if (i < ns) atomicAdd(&cnt_src[lab], 1);
    int pos = atomicAdd(&fill[lab], 1);
    clsrows[(size_t)lab * N + pos] = i;
}

// scan: padded row offsets (32-aligned per present class) + upper-tri tile offsets
__device__ __forceinline__ void scan_offsets2(const int* __restrict__ cnt_src,
                                              const int* __restrict__ fill, int C,
                                              int* proS, int* tpoS, int* tS, int* presS,
                                              int* padTotS, int* nTilesS) {
    if (threadIdx.x < 64) {
        int lane = threadIdx.x;
        int n = (lane < C) ? fill[lane] : 0;
        int nsrc = (lane < C) ? cnt_src[lane] : 0;
        int pres = (nsrc > 0 && (n - nsrc) > 0) ? 1 : 0;
        int T = pres ? (n + TILE - 1) / TILE : 0;
        int prw = T * 32;                 // padded rows
        int t2 = T * (T + 1) / 2;         // upper-triangle tiles
        int sp = prw, st = t2;
        for (int o = 1; o < 64; o <<= 1) {
            int a = __shfl_up(sp, o), b = __shfl_up(st, o);
            if (lane >= o) { sp += a; st += b; }
        }
        if (lane < C) {
            proS[lane] = sp - prw; tpoS[lane] = st - t2;
            tS[lane] = T; presS[lane] = pres;
        }
        if (lane == C - 1) { proS[C] = sp; tpoS[C] = st; *padTotS = sp; *nTilesS = st; }
    }
    __syncthreads();
}

// ---- gather: 16-row panel per block -> fragment-major Xp + sq/sign/sqsum/classum ----
__global__ __launch_bounds__(256) void k_gather(
        const float* __restrict__ src, const float* __restrict__ tgt,
        const int* __restrict__ clsrows,
        const int* __restrict__ cnt_src, const int* __restrict__ fill,
        int ns, int N, int D, int C,
        unsigned short* __restrict__ Xp, float* __restrict__ sqg, float* __restrict__ sgg,
        double* __restrict__ sqsum, float* __restrict__ classum) {
    __shared__ int proS[65], tpoS[65], tS[64], presS[64], padTotS, nTilesS;
    scan_offsets2(cnt_src, fill, C, proS, tpoS, tS, presS, &padTotS, &nTilesS);
    int p = blockIdx.x;
    int s0 = p * 16;
    if (s0 >= padTotS) return;
    int tid = threadIdx.x;
    int lane = tid & 63;
    int wv = tid >> 6;
    int c = __popcll(__ballot((lane < C) && (proS[lane] <= s0))) - 1;
    int n = fill[c];
    int idx0 = s0 - proS[c];

    __shared__ unsigned short Ls[16][2048 + 8];   // +8 u16 pad: phase-2 reads ~conflict-free
    __shared__ float ls4[16][4];
    float cs[8];
    #pragma unroll
    for (int j = 0; j < 8; j++) cs[j] = 0.f;

    for (int r = 0; r < 16; r++) {
        int idx = idx0 + r;
        bool valid = idx < n;
        float4 v0 = {0.f, 0.f, 0.f, 0.f}, v1 = v0;
        if (valid) {
            int g = clsrows[(size_t)c * N + idx];
            const float* row = (g < ns) ? src + (size_t)g * D : tgt + (size_t)(g - ns) * D;
            v0 = *(const float4*)(row + tid * 8);
            v1 = *(const float4*)(row + tid * 8 + 4);
        }
        cs[0] += v0.x; cs[1] += v0.y; cs[2] += v0.z; cs[3] += v0.w;
        cs[4] += v1.x; cs[5] += v1.y; cs[6] += v1.z; cs[7] += v1.w;
        float a = v0.x*v0.x + v0.y*v0.y + v0.z*v0.z + v0.w*v0.w
                + v1.x*v1.x + v1.y*v1.y + v1.z*v1.z + v1.w*v1.w;
        for (int o = 32; o; o >>= 1) a += __shfl_down(a, o);
        if (lane == 0) ls4[r][wv] = a;
        uint4 pk;
        pk.x = f2bf(v0.x) | (f2bf(v0.y) << 16);
        pk.y = f2bf(v0.z) | (f2bf(v0.w) << 16);
        pk.z = f2bf(v1.x) | (f2bf(v1.y) << 16);
        pk.w = f2bf(v1.z) | (f2bf(v1.w) << 16);
        *(uint4*)&Ls[r][tid * 8] = pk;
    }
    #pragma unroll
    for (int j = 0; j < 8; j++)
        atomicAdd(&classum[(size_t)c * D + tid * 8 + j], cs[j]);
    __syncthreads();
    if (tid < 16) {
        int idx = idx0 + tid;
        bool valid = idx < n;
        float sq = ls4[tid][0] + ls4[tid][1] + ls4[tid][2] + ls4[tid][3];
        int g = valid ? clsrows[(size_t)c * N + idx] : 0;
        sqg[s0 + tid] = valid ? sq : 0.f;
        sgg[s0 + tid] = valid ? ((g < ns) ? 1.f : -1.f) : 0.f;
    }
    if (tid == 0) {
        double tot = 0.0;
        for (int r = 0; r < 16; r++)
            tot += (double)(ls4[r][0] + ls4[r][1] + ls4[r][2] + ls4[r][3]);
        atomicAdd(&sqsum[c], tot);
    }
    // phase 2: fragment-major write  Xp[(p*256 + k8)*128 + pr*8 .. +8]
    int pr = tid & 15, kq = tid >> 4;
    size_t pb = (size_t)p * 32768;    // u16 units per panel (16 rows * 2048)
    for (int o = 0; o < 16; o++) {
        int k8 = kq * 16 + o;
        uint4 val = *(uint4*)&Ls[pr][k8 * 8];
        *(uint4*)(Xp + pb + (size_t)k8 * 128 + pr * 8) = val;
    }
}

// ---- per-class bandwidth from closed form ----
__global__ void k_bw(const float* __restrict__ classum, const double* __restrict__ sqsum,
                     const int* __restrict__ cnt_src, const int* __restrict__ fill,
                     int D, int C, float* __restrict__ invbw) {
    int c = blockIdx.x;
    int tid = threadIdx.x;
    int n = fill[c], nsrc = cnt_src[c];
    int pres = (nsrc > 0 && (n - nsrc) > 0) ? 1 : 0;
    const float* cp = classum + (size_t)c * D;
    double sn = 0.0;
    for (int d = tid; d < D; d += 256) { double v = (double)cp[d]; sn += v * v; }
    for (int o = 32; o; o >>= 1) sn += __shfl_down(sn, o);
    __shared__ double ls[4];
    if ((tid & 63) == 0) ls[tid >> 6] = sn;
    __syncthreads();
    if (tid == 0) {
        double snorm = ls[0] + ls[1] + ls[2] + ls[3];
        double l2 = 2.0 * (double)n * sqsum[c] - 2.0 * snorm;
        double den = (double)n * (double)n - (double)n; if (den < 1.0) den = 1.0;
        double bw = l2 / den / 4.0;          // bw_scale = KERNEL_MUL^(KERNEL_NUM//2)
        bw = pres ? fmax(bw, 1e-20) : 1.0;
        double m = 1.0;
        for (int k = 0; k < 5; k++) { invbw[c * 5 + k] = (float)(1.0 / (bw * m)); m *= 2.0; }
    }
}

// ---- fused pair kernel: block = (class, ti<=tj tile); 4 waves split-K; in-block epi ----
__global__ __launch_bounds__(256) void k_pairs(
        const unsigned short* __restrict__ Xp, const float* __restrict__ sqg,
        const float* __restrict__ sgg, const float* __restrict__ invbw,
        const int* __restrict__ cnt_src, const int* __restrict__ fill,
        int N, int D, int C, double* __restrict__ contrib) {
    __shared__ int proS[65], tpoS[65], tS[64], presS[64], padTotS, nTilesS;
    scan_offsets2(cnt_src, fill, C, proS, tpoS, tS, presS, &padTotS, &nTilesS);
    __shared__ float Lp[4 * 16 * 64];        // [wv][frag fi*2+fj][r][lane] = 16 KB
    __shared__ float sqA[32], sgA[32], sqB[32], sgB[32];

    int tid = threadIdx.x, lane = tid & 63, wv = tid >> 6;
    int kgrp = lane >> 4, lr = lane & 15;
    int nTiles = nTilesS;

    for (int job = blockIdx.x; job < nTiles; job += gridDim.x) {
        __syncthreads();                      // protect LDS from previous job
        int c = __popcll(__ballot((lane < C) && (tpoS[lane] <= job))) - 1;
        int t = job - tpoS[c];
        int T = tS[c];
        int ti = 0, rem = t;
        while (rem >= T - ti) { rem -= (T - ti); ti++; }   // upper-triangle decode
        int tj = ti + rem;
        int pbase = proS[c];
        int n = fill[c];
        float wgt = (ti == tj) ? 1.f : 2.f;   // gram symmetry

        if (tid < 32) {
            sqA[tid] = sqg[pbase + ti * 32 + tid];
            sgA[tid] = sgg[pbase + ti * 32 + tid];
        } else if (tid < 64) {
            int j = tid - 32;
            sqB[j] = sqg[pbase + tj * 32 + j];
            sgB[j] = sgg[pbase + tj * 32 + j];
        }

        size_t pA0 = ((size_t)(pbase >> 4) + ti * 2) * 32768;   // u16 units
        size_t pA1 = pA0 + 32768;
        size_t pB0 = ((size_t)(pbase >> 4) + tj * 2) * 32768;
        size_t pB1 = pB0 + 32768;
        int k8base = wv * 64;                 // this wave's K-quarter (512 dims)

        f32x4 a00 = (f32x4){0.f, 0.f, 0.f, 0.f}, a01 = a00, a10 = a00, a11 = a00;
        #pragma unroll 4
        for (int ks = 0; ks < 16; ks++) {
            size_t off = (size_t)(k8base + ks * 4 + kgrp) * 128 + lr * 8;
            bf16x8 va0 = *(const bf16x8*)(Xp + pA0 + off);
            bf16x8 va1 = *(const bf16x8*)(Xp + pA1 + off);
            bf16x8 vb0 = *(const bf16x8*)(Xp + pB0 + off);
            bf16x8 vb1 = *(const bf16x8*)(Xp + pB1 + off);
            a00 = __builtin_amdgcn_mfma_f32_16x16x32_bf16(va0, vb0, a00, 0, 0, 0);
            a01 = __builtin_amdgcn_mfma_f32_16x16x32_bf16(va0, vb1, a01, 0, 0, 0);
            a10 = __builtin_amdgcn_mfma_f32_16x16x32_bf16(va1, vb0, a10, 0, 0, 0);
            a11 = __builtin_amdgcn_mfma_f32_16x16x32_bf16(va1, vb1, a11, 0, 0, 0);
        }
        #pragma unroll
        for (int r = 0; r < 4; r++) {
            Lp[((wv * 4 + 0) * 4 + r) * 64 + lane] = a00[r];
            Lp[((wv * 4 + 1) * 4 + r) * 64 + lane] = a01[r];
            Lp[((wv * 4 + 2) * 4 + r) * 64 + lane] = a10[r];
            Lp[((wv * 4 + 3) * 4 + r) * 64 + lane] = a11[r];
        }
        __syncthreads();

        float ib0 = invbw[c * 5 + 0], ib1 = invbw[c * 5 + 1], ib2 = invbw[c * 5 + 2];
        float ib3 = invbw[c * 5 + 3], ib4 = invbw[c * 5 + 4];
        int i = tid >> 3;                     // 0..31
        int j0 = (tid & 7) * 4;
        bool vi = (ti * 32 + i) < n;
        float sa = sqA[i], ga = sgA[i];
        float ts = 0.f;
        #pragma unroll
        for (int q = 0; q < 4; q++) {
            int j = j0 + q;
            bool vj = (tj * 32 + j) < n;
            int f = (i >> 4) * 2 + (j >> 4);
            int le = ((i & 15) >> 2) * 16 + (j & 15);   // m89 C/D layout
            int r = i & 3;
            float dot = Lp[((0 * 4 + f) * 4 + r) * 64 + le]
                      + Lp[((1 * 4 + f) * 4 + r) * 64 + le]
                      + Lp[((2 * 4 + f) * 4 + r) * 64 + le]
                      + Lp[((3 * 4 + f) * 4 + r) * 64 + le];
            if (vi && vj) {
                float D2 = sa + sqB[j] - 2.f * dot;
                float e = expf(-D2 * ib0) + expf(-D2 * ib1) + expf(-D2 * ib2)
                        + expf(-D2 * ib3) + expf(-D2 * ib4);
                ts += ga * sgB[j] * e;
            }
        }
        double ds = (double)(ts * wgt);
        for (int o = 32; o; o >>= 1) ds += __shfl_down(ds, o);
        if (lane == 0) atomicAdd(&contrib[c], ds);
    }
}

__global__ void k_final(const double* __restrict__ contrib,
                        const int* __restrict__ cnt_src, const int* __restrict__ fill,
                        int C, float* __restrict__ out) {
    int c = threadIdx.x;
    double l = 0.0, k = 0.0;
    if (c < C) {
        int n = fill[c], nsrc = cnt_src[c];
        if (nsrc > 0 && (n - nsrc) > 0) {
            double nn = (double)n * (double)n; if (nn < 1.0) nn = 1.0;
            l = contrib[c] / nn; k = 1.0;
        }
    }
    for (int o = 32; o; o >>= 1) { l += __shfl_down(l, o); k += __shfl_down(k, o); }
    if (c == 0) out[0] = (float)(l / k);
}

extern "C" void kernel_launch(void* const* d_in, const int* in_sizes, int n_in,
                              void* d_out, int out_size, void* d_ws, size_t ws_size,
                              hipStream_t stream) {
    const float* src  = (const float*)d_in[0];
    const float* tgt  = (const float*)d_in[1];
    const int*   slab = (const int*)d_in[2];
    const float* tlab = (const float*)d_in[3];
    const int ns = in_sizes[2];
    const int D  = in_sizes[0] / ns;
    const int nt = in_sizes[1] / D;
    const int C  = in_sizes[3] / nt;
    const int N  = ns + nt;
    const int padN = N + 32 * C;            // upper bound on padded slots

    char* w = (char*)d_ws;
    size_t off = 0;
    auto take = [&](size_t bytes) -> char* {
        char* p = w + off;
        off = (off + bytes + 255) & ~(size_t)255;
        return p;
    };
    // --- zero region (memset below) ---
    int*    cnt_src = (int*)take(64 * sizeof(int));
    int*    fill    = (int*)take(64 * sizeof(int));
    double* sqsum   = (double*)take(64 * sizeof(double));
    double* contrib = (double*)take(64 * sizeof(double));
    float*  classum = (float*)take((size_t)C * D * sizeof(float));
    size_t zbytes = off;
    // --- rest ---
    int*            clsrows = (int*)take((size_t)C * N * sizeof(int));
    float*          sqg     = (float*)take((size_t)padN * sizeof(float));
    float*          sgg     = (float*)take((size_t)padN * sizeof(float));
    float*          invbw   = (float*)take((size_t)C * 5 * sizeof(float));
    unsigned short* Xp      = (unsigned short*)take((size_t)padN * D * sizeof(unsigned short));
    (void)n_in; (void)out_size; (void)ws_size;

    hipMemsetAsync(d_ws, 0, zbytes, stream);
    k_prep<<<(N + 255) / 256, 256, 0, stream>>>(slab, tlab, ns, N, C, clsrows, cnt_src, fill);
    k_gather<<<(padN + 15) / 16, 256, 0, stream>>>(src, tgt, clsrows, cnt_src, fill,
                                                   ns, N, D, C, Xp, sqg, sgg, sqsum, classum);
    k_bw<<<C, 256, 0, stream>>>(classum, sqsum, cnt_src, fill, D, C, invbw);
    k_pairs<<<1024, 256, 0, stream>>>(Xp, sqg, sgg, invbw, cnt_src, fill, N, D, C, contrib);
    k_final<<<1, 64, 0, stream>>>(contrib, cnt_src, fill, C, (float*)d_out);
}